// Round 8
// baseline (808.247 us; speedup 1.0000x reference)
//
#include <hip/hip_runtime.h>
#include <math.h>

#define LDIM 8192   // H*W = 16*512
#define NC   512
#define NM   1024

typedef unsigned short u16;
typedef unsigned int   u32;
typedef short bf16x8 __attribute__((ext_vector_type(8)));
typedef float f32x4  __attribute__((ext_vector_type(4)));

static constexpr float kEps        = 1e-4f;
static constexpr float kInvSqrt512 = 0.044194173824159216f;
static constexpr float kInvSqrt1024= 0.03125f;
static constexpr float kInvSqrt1152= 0.029462782549439483f;
static constexpr float kQScale     = 0.08838834764831845f;   // 1/sqrt(128)
static constexpr float kLog2e      = 1.4426950408889634f;
static constexpr float kInvSqrt2   = 0.7071067811865476f;
static constexpr float kInvSilu    = 1.0f / 0.596f;

__device__ __forceinline__ u16 f2bf(float f) {
    u32 u = __float_as_uint(f);
    u += 0x7fff + ((u >> 16) & 1);
    return (u16)(u >> 16);
}
__device__ __forceinline__ float bf2f(u16 h) { return __uint_as_float((u32)h << 16); }
__device__ __forceinline__ uint2 pk4(float a, float b, float c, float d) {
    uint2 r;
    r.x = (u32)f2bf(a) | ((u32)f2bf(b) << 16);
    r.y = (u32)f2bf(c) | ((u32)f2bf(d) << 16);
    return r;
}

// ---------------------------------------------------------------------------
#define N_W0 524288
#define N_W1 524288
#define N_WQ 1048576
#define N_WV 262144
#define N_WT 1179648
__global__ void k_prep_w(const float* __restrict__ w0, const float* __restrict__ w1,
                         const float* __restrict__ wq, const float* __restrict__ wv,
                         const float* __restrict__ wd,
                         u16* __restrict__ w0b, u16* __restrict__ w1b,
                         u16* __restrict__ wqb, u16* __restrict__ wvb,
                         u16* __restrict__ wtb) {
    const int total = N_W0 + N_W1 + N_WQ + N_WV + N_WT;
    for (int i = blockIdx.x * 256 + threadIdx.x; i < total; i += gridDim.x * 256) {
        int idx = i;
        if (idx < N_W0) { w0b[idx] = f2bf(w0[idx]); continue; }
        idx -= N_W0;
        if (idx < N_W1) { w1b[idx] = f2bf(w1[idx]); continue; }
        idx -= N_W1;
        if (idx < N_WQ) { wqb[idx] = f2bf(wq[idx]); continue; }
        idx -= N_WQ;
        if (idx < N_WV) { wvb[idx] = f2bf(wv[idx]); continue; }
        idx -= N_WV;
        int tap = idx >> 17;
        int rem = idx & 131071;
        int co = rem >> 7, ci = rem & 127;
        wtb[idx] = f2bf(wd[(co * 128 + ci) * 9 + tap]);
    }
}

__global__ void k_emb(const float* __restrict__ w_emb, const float* __restrict__ emb,
                      const float* __restrict__ eg, float* __restrict__ cvec) {
    int wave = threadIdx.x >> 6, lane = threadIdx.x & 63;
    int m = blockIdx.x * 4 + wave;
    float s = 0.f;
    for (int e = lane; e < 512; e += 64) s += w_emb[(size_t)m * 512 + e] * emb[e];
    for (int off = 32; off; off >>= 1) s += __shfl_down(s, off);
    if (lane == 0) cvec[m] = eg[0] * kInvSqrt512 * s + 1.0f;
}

// ---------------------------------------------------------------------------
__global__ void k_rn(const float* __restrict__ x, float* __restrict__ rn) {
    __shared__ float red[4][64];
    int t = threadIdx.x;
    int ll = t & 63, qtr = t >> 6;
    int l = blockIdx.x * 64 + ll;
    float ss = 0.f;
    for (int c = qtr * 128; c < (qtr + 1) * 128; ++c) {
        float v = x[(size_t)c * LDIM + l];
        ss += v * v;
    }
    red[qtr][ll] = ss;
    __syncthreads();
    if (t < 64)
        rn[blockIdx.x * 64 + t] =
            1.f / (kEps + sqrtf((red[0][t] + red[1][t] + red[2][t] + red[3][t]) * (1.0f / 512.0f)));
}

__launch_bounds__(256)
__global__ void k_tr2(const float* __restrict__ in, const float* __restrict__ rn,
                      u16* __restrict__ out) {
    __shared__ float T[64][65];
    const int t = threadIdx.x;
    const int l0 = blockIdx.x * 64, c0 = blockIdx.y * 64;
    #pragma unroll
    for (int i = 0; i < 16; ++i) {
        int idx = t + 256 * i;
        int ci = idx >> 6, ll = idx & 63;
        T[ci][ll] = in[(size_t)(c0 + ci) * LDIM + l0 + ll];
    }
    __syncthreads();
    int lo = t >> 2, cc0 = (t & 3) * 16;
    float s = rn ? rn[l0 + lo] : 1.0f;
    u16 tmp[16];
    #pragma unroll
    for (int j = 0; j < 16; ++j) tmp[j] = f2bf(T[cc0 + j][lo] * s);
    u16* dst = out + (size_t)(l0 + lo) * 512 + c0 + cc0;
    *(uint4*)dst = *(uint4*)&tmp[0];
    *(uint4*)(dst + 8) = *(uint4*)&tmp[8];
}

__launch_bounds__(256)
__global__ void k_tr_b2x(const u16* __restrict__ in, void* __restrict__ outp, int mode) {
    __shared__ u16 T[64][72];
    const int t = threadIdx.x;
    const int lt = blockIdx.x & 127, ct = blockIdx.x >> 7;
    const int l0 = lt * 64, c0 = ct * 64;
    #pragma unroll
    for (int i = 0; i < 2; ++i) {
        int c = t + 256 * i;
        int ll = c >> 3, cc = c & 7;
        *(uint4*)&T[ll][cc * 8] = *(const uint4*)(in + (size_t)(l0 + ll) * 512 + c0 + cc * 8);
    }
    __syncthreads();
    int ll = t & 63;
    if (mode == 0) {
        float* out = (float*)outp;
        #pragma unroll
        for (int i = 0; i < 16; ++i) {
            int cj = (t >> 6) + 4 * i;
            out[(size_t)(c0 + cj) * LDIM + l0 + ll] = bf2f(T[ll][cj]);
        }
    } else {
        u16* out = (u16*)outp;
        #pragma unroll
        for (int i = 0; i < 16; ++i) {
            int cj = (t >> 6) + 4 * i;
            out[(size_t)(c0 + cj) * LDIM + l0 + ll] = T[ll][cj];
        }
    }
}

// ---------------------------------------------------------------------------
__launch_bounds__(256, 2)
__global__ void k_gemm_tm(const u16* __restrict__ Xt, const u16* __restrict__ W,
                          u16* __restrict__ Out, int K, int M, float scale) {
    __shared__ u16 sm[18432];
    u16* Xs = sm;
    u16* Ws = sm + 9216;
    u16* Sout = sm;
    const int t = threadIdx.x;
    const int lane = t & 63, wave = t >> 6;
    const int quad = lane >> 4, ln = lane & 15;
    const int l0 = blockIdx.x * 128, m0 = blockIdx.y * 128;
    const int cs = (wave & 1) * 64, ls = (wave >> 1) * 64;

    #pragma unroll
    for (int i = 0; i < 4; ++i) {
        int c = t + 256 * i;
        int row = c >> 3, cc = c & 7;
        *(uint4*)&Xs[row * 72 + cc * 8] = *(const uint4*)(Xt + (size_t)(l0 + row) * K + cc * 8);
        *(uint4*)&Ws[row * 72 + cc * 8] = *(const uint4*)(W + (size_t)(m0 + row) * K + cc * 8);
    }
    __syncthreads();

    f32x4 acc[4][4] = {};
    for (int k0 = 0; k0 < K; k0 += 64) {
        uint4 px[4], pw[4];
        const bool pf = (k0 + 64 < K);
        if (pf) {
            #pragma unroll
            for (int i = 0; i < 4; ++i) {
                int c = t + 256 * i;
                int row = c >> 3, cc = c & 7;
                px[i] = *(const uint4*)(Xt + (size_t)(l0 + row) * K + k0 + 64 + cc * 8);
                pw[i] = *(const uint4*)(W + (size_t)(m0 + row) * K + k0 + 64 + cc * 8);
            }
        }
        #pragma unroll
        for (int ks = 0; ks < 2; ++ks) {
            bf16x8 af[4], bf[4];
            #pragma unroll
            for (int mt = 0; mt < 4; ++mt)
                af[mt] = *(const bf16x8*)&Ws[(cs + mt * 16 + ln) * 72 + ks * 32 + quad * 8];
            #pragma unroll
            for (int nt = 0; nt < 4; ++nt)
                bf[nt] = *(const bf16x8*)&Xs[(ls + nt * 16 + ln) * 72 + ks * 32 + quad * 8];
            #pragma unroll
            for (int mt = 0; mt < 4; ++mt)
                #pragma unroll
                for (int nt = 0; nt < 4; ++nt)
                    acc[mt][nt] = __builtin_amdgcn_mfma_f32_16x16x32_bf16(af[mt], bf[nt], acc[mt][nt], 0, 0, 0);
        }
        __syncthreads();
        if (pf) {
            #pragma unroll
            for (int i = 0; i < 4; ++i) {
                int c = t + 256 * i;
                int row = c >> 3, cc = c & 7;
                *(uint4*)&Xs[row * 72 + cc * 8] = px[i];
                *(uint4*)&Ws[row * 72 + cc * 8] = pw[i];
            }
        }
        __syncthreads();
    }
    #pragma unroll
    for (int mt = 0; mt < 4; ++mt)
        #pragma unroll
        for (int nt = 0; nt < 4; ++nt) {
            f32x4 a = acc[mt][nt];
            *(uint2*)&Sout[(ls + nt * 16 + ln) * 136 + cs + mt * 16 + quad * 4] =
                pk4(a[0] * scale, a[1] * scale, a[2] * scale, a[3] * scale);
        }
    __syncthreads();
    #pragma unroll
    for (int i = 0; i < 8; ++i) {
        int c = t + 256 * i;
        int row = c >> 4, cc = c & 15;
        *(uint4*)(Out + (size_t)(l0 + row) * M + m0 + cc * 8) = *(uint4*)&Sout[row * 136 + cc * 8];
    }
}

// ---------------------------------------------------------------------------
__launch_bounds__(256, 4)
__global__ void k_gconv_tm(const u16* __restrict__ y1t, const u16* __restrict__ wtb,
                           const float* __restrict__ cvec, u16* __restrict__ y2t) {
    __shared__ u16 sm[9792];
    u16* Y = sm;
    u16* Sout = sm;
    const int t = threadIdx.x;
    const int lane = t & 63, wave = t >> 6;
    const int quad = lane >> 4, ln = lane & 15;
    const int l0 = blockIdx.x * 64;
    const int m0 = blockIdx.y * 128;
    const int g = m0 >> 7;

    for (int c = t; c < 1152; c += 256) {
        int row = c >> 4, cc = c & 15;
        int gl = l0 - 4 + row;
        gl = min(max(gl, 0), LDIM - 1);
        *(uint4*)&Y[row * 136 + cc * 8] = *(const uint4*)(y1t + (size_t)gl * 1024 + g * 128 + cc * 8);
    }
    __syncthreads();

    f32x4 acc[2][4] = {};
    const bf16x8 zv = {};
    for (int tap = 0; tap < 9; ++tap) {
        #pragma unroll
        for (int ks = 0; ks < 4; ++ks) {
            bf16x8 af[2], bfr[4];
            #pragma unroll
            for (int mt = 0; mt < 2; ++mt)
                af[mt] = *(const bf16x8*)(wtb + ((size_t)tap * 1024 + m0 + wave * 32 + mt * 16 + ln) * 128 + ks * 32 + quad * 8);
            #pragma unroll
            for (int nt = 0; nt < 4; ++nt) {
                bfr[nt] = *(const bf16x8*)&Y[(nt * 16 + ln + tap) * 136 + ks * 32 + quad * 8];
                int w = ((l0 + nt * 16 + ln) & 511) + tap - 4;
                bool ok = (w >= 0) && (w < 512);
                bfr[nt] = ok ? bfr[nt] : zv;
            }
            #pragma unroll
            for (int mt = 0; mt < 2; ++mt)
                #pragma unroll
                for (int nt = 0; nt < 4; ++nt)
                    acc[mt][nt] = __builtin_amdgcn_mfma_f32_16x16x32_bf16(af[mt], bfr[nt], acc[mt][nt], 0, 0, 0);
        }
    }
    __syncthreads();
    #pragma unroll
    for (int mt = 0; mt < 2; ++mt) {
        float4 cv = *(const float4*)(cvec + m0 + wave * 32 + mt * 16 + quad * 4);
        #pragma unroll
        for (int nt = 0; nt < 4; ++nt) {
            float z[4], o[4];
            #pragma unroll
            for (int r = 0; r < 4; ++r) {
                z[r] = acc[mt][nt][r] * kInvSqrt1152 * ((const float*)&cv)[r];
                float sig = 1.0f / (1.0f + __expf(-z[r]));
                o[r] = z[r] * sig * kInvSilu;
            }
            *(uint2*)&Sout[(nt * 16 + ln) * 136 + wave * 32 + mt * 16 + quad * 4] =
                pk4(o[0], o[1], o[2], o[3]);
        }
    }
    __syncthreads();
    #pragma unroll
    for (int i = 0; i < 4; ++i) {
        int c = t + 256 * i;
        int row = c >> 4, cc = c & 15;
        *(uint4*)(y2t + (size_t)(l0 + row) * 1024 + m0 + cc * 8) = *(uint4*)&Sout[row * 136 + cc * 8];
    }
}

// ---------------------------------------------------------------------------
__global__ void k_mpsum_t(const u16* __restrict__ a, const u16* __restrict__ b,
                          u16* __restrict__ out) {
    size_t base = ((size_t)blockIdx.x * 256 + threadIdx.x) * 8;
    uint4 av = *(const uint4*)(a + base);
    uint4 bv = *(const uint4*)(b + base);
    const u16* ap = (const u16*)&av;
    const u16* bp = (const u16*)&bv;
    u16 o[8];
    #pragma unroll
    for (int i = 0; i < 8; ++i) o[i] = f2bf((bf2f(ap[i]) + bf2f(bp[i])) * kInvSqrt2);
    *(uint4*)(out + base) = *(uint4*)o;
}

__global__ void k_pe_t(const u16* __restrict__ xs, const u16* __restrict__ pos,
                       u16* __restrict__ pe) {
    int idx = blockIdx.x * 256 + threadIdx.x;
    int l = idx >> 6, cq = idx & 63;
    size_t src = (size_t)l * 512 + cq * 8;
    uint4 xv = *(const uint4*)(xs + src);
    uint4 pv = *(const uint4*)(pos + src);
    const u16* xp = (const u16*)&xv;
    const u16* pp = (const u16*)&pv;
    u16 o[16];
    #pragma unroll
    for (int i = 0; i < 8; ++i) {
        o[2 * i] = xp[i];
        o[2 * i + 1] = f2bf(bf2f(xp[i]) * bf2f(pp[i]));
    }
    u16* dst = pe + (size_t)l * 1024 + cq * 16;
    *(uint4*)dst = *(uint4*)&o[0];
    *(uint4*)(dst + 8) = *(uint4*)&o[8];
}

// ---------------------------------------------------------------------------
// q scaled by log2e/sqrt(d) so attention can use exp2 (native v_exp_f32).
__global__ void k_norm_qk2(const u16* __restrict__ qk, u16* __restrict__ q_t,
                           u16* __restrict__ k_t) {
    int wave = threadIdx.x >> 6, lane = threadIdx.x & 63;
    int l = blockIdx.x * 4 + wave;
    const u16* row = qk + (size_t)l * 1024 + lane * 16;
    uint4 a = *(const uint4*)row;
    uint4 b = *(const uint4*)(row + 8);
    const u16* vp = (const u16*)&a;
    const u16* wp = (const u16*)&b;
    float v[16];
    #pragma unroll
    for (int i = 0; i < 8; ++i) { v[i] = bf2f(vp[i]); v[8 + i] = bf2f(wp[i]); }
    float ss0 = 0.f, ss1 = 0.f;
    #pragma unroll
    for (int i = 0; i < 8; ++i) { ss0 += v[2 * i] * v[2 * i]; ss1 += v[2 * i + 1] * v[2 * i + 1]; }
    #pragma unroll
    for (int off = 1; off < 16; off <<= 1) {
        ss0 += __shfl_xor(ss0, off);
        ss1 += __shfl_xor(ss1, off);
    }
    float rn0 = (kQScale * kLog2e) / (kEps + sqrtf(ss0 * (1.0f / 128.0f)));
    float rn1 = 1.0f / (kEps + sqrtf(ss1 * (1.0f / 128.0f)));
    int h = lane >> 4;
    u16 qo[8], ko[8];
    #pragma unroll
    for (int i = 0; i < 8; ++i) {
        qo[i] = f2bf(v[2 * i] * rn0);
        ko[i] = f2bf(v[2 * i + 1] * rn1);
    }
    size_t dst = ((size_t)h * LDIM + l) * 128 + (lane & 15) * 8;
    *(uint4*)(q_t + dst) = *(uint4*)qo;
    *(uint4*)(k_t + dst) = *(uint4*)ko;
}

__global__ void k_norm_v2(u16* __restrict__ v_t) {
    int wave = threadIdx.x >> 6, lane = threadIdx.x & 63;
    int l = blockIdx.x * 4 + wave;
    u16* p = v_t + (size_t)l * 512 + lane * 8;
    uint4 a = *(const uint4*)p;
    const u16* vp = (const u16*)&a;
    float v[8], ss = 0.f;
    #pragma unroll
    for (int i = 0; i < 8; ++i) { v[i] = bf2f(vp[i]); ss += v[i] * v[i]; }
    #pragma unroll
    for (int off = 1; off < 16; off <<= 1) ss += __shfl_xor(ss, off);
    float rn = 1.0f / (kEps + sqrtf(ss * (1.0f / 128.0f)));
    u16 o[8];
    #pragma unroll
    for (int i = 0; i < 8; ++i) o[i] = f2bf(v[i] * rn);
    *(uint4*)p = *(uint4*)o;
}

// ---------------------------------------------------------------------------
// MFMA flash attention v7. Grid = 256 blocks x 512 threads (K-split 2,
// combo = b&7 -> one K/V slice per XCD). Wave tile 64 rows x 32 j (v6).
// New: (1) double-buffered K/V LDS -> ONE barrier/iter (v6 had 2 + vmcnt
// drain: phase-locked waves serialized MFMA/VALU/LDS pipes);
// (2) exp2 with log2e folded into q scale; (3) row sums via MFMA with
// ones-fragment (no VALU adds, no shuffles); (4) hf-pairs merge O in LDS,
// global O write back to v5's 2-way/16MB scheme (v6's 4-way split caused
// 7x write amplification: 230 MB).
#define PZ 72
__launch_bounds__(512, 1)
__global__ void k_attn7(const u16* __restrict__ q_t, const u16* __restrict__ k_t,
                        const u16* __restrict__ vt2, u16* __restrict__ Opart,
                        float* __restrict__ lsumG) {
    __shared__ u16 Ks[2][64 * 136];   // [buf][j][d]
    __shared__ u16 Vs[2][128 * 72];   // [buf][d][j]
    __shared__ u16 Ps[256 * PZ];      // [i][j]; also f32 scratch in epilogue
    const int t = threadIdx.x;
    const int lane = t & 63, wave = t >> 6;   // 0..7
    const int quad = lane >> 4, ln = lane & 15;
    const int b = blockIdx.x;
    const int h = (b >> 1) & 3, sp = b & 1;
    const int i0 = (b >> 3) * 256;
    const int jb0 = sp * 4096, jend = jb0 + 4096;
    const int strip = (wave >> 1) * 64;
    const int hf = wave & 1;
    const u16* qg = q_t + (size_t)h * LDIM * 128;
    const u16* kg = k_t + (size_t)h * LDIM * 128;
    const u16* vg = vt2 + (size_t)h * 128 * LDIM;

    bf16x8 qf[4][4];
    #pragma unroll
    for (int mt = 0; mt < 4; ++mt) {
        int row = i0 + strip + mt * 16 + ln;
        #pragma unroll
        for (int ks = 0; ks < 4; ++ks)
            qf[mt][ks] = *(const bf16x8*)(qg + (size_t)row * 128 + ks * 32 + quad * 8);
    }

    const bf16x8 ones = {(short)0x3F80, (short)0x3F80, (short)0x3F80, (short)0x3F80,
                         (short)0x3F80, (short)0x3F80, (short)0x3F80, (short)0x3F80};
    f32x4 o_acc[4][8] = {};
    f32x4 lsum_acc[4] = {};

    // stage tile 0 into buf 0
    #pragma unroll
    for (int i = 0; i < 2; ++i) {
        int c = t + 512 * i;
        *(uint4*)&Ks[0][(c >> 4) * 136 + (c & 15) * 8] =
            *(const uint4*)(kg + (size_t)(jb0 + (c >> 4)) * 128 + (c & 15) * 8);
        *(uint4*)&Vs[0][(c >> 3) * 72 + (c & 7) * 8] =
            *(const uint4*)(vg + (size_t)(c >> 3) * LDIM + jb0 + (c & 7) * 8);
    }
    // preload tile 1 into registers
    uint4 kxA[2], vxA[2];
    #pragma unroll
    for (int i = 0; i < 2; ++i) {
        int c = t + 512 * i;
        kxA[i] = *(const uint4*)(kg + (size_t)(jb0 + 64 + (c >> 4)) * 128 + (c & 15) * 8);
        vxA[i] = *(const uint4*)(vg + (size_t)(c >> 3) * LDIM + jb0 + 64 + (c & 7) * 8);
    }
    __syncthreads();

    int cur = 0;
    for (int jb = jb0; jb < jend; jb += 64) {
        const bool pf1 = (jb + 64 < jend);
        const bool pf2 = (jb + 128 < jend);
        uint4 kxB[2], vxB[2];
        if (pf2) {
            #pragma unroll
            for (int i = 0; i < 2; ++i) {
                int c = t + 512 * i;
                kxB[i] = *(const uint4*)(kg + (size_t)(jb + 128 + (c >> 4)) * 128 + (c & 15) * 8);
                vxB[i] = *(const uint4*)(vg + (size_t)(c >> 3) * LDIM + jb + 128 + (c & 7) * 8);
            }
        }
        const u16* Kc = Ks[cur];
        const u16* Vc = Vs[cur];
        // S^T for this wave's 32-j half x 64 rows
        f32x4 st[2][4] = {};
        #pragma unroll
        for (int ks = 0; ks < 4; ++ks) {
            bf16x8 af0 = *(const bf16x8*)&Kc[(hf * 32 + ln) * 136 + ks * 32 + quad * 8];
            bf16x8 af1 = *(const bf16x8*)&Kc[(hf * 32 + 16 + ln) * 136 + ks * 32 + quad * 8];
            #pragma unroll
            for (int mt = 0; mt < 4; ++mt) {
                st[0][mt] = __builtin_amdgcn_mfma_f32_16x16x32_bf16(af0, qf[mt][ks], st[0][mt], 0, 0, 0);
                st[1][mt] = __builtin_amdgcn_mfma_f32_16x16x32_bf16(af1, qf[mt][ks], st[1][mt], 0, 0, 0);
            }
        }
        // P = exp2(S') (fixed-max safe: |S'| <= sqrt(d)*log2e ~ 16.3)
        #pragma unroll
        for (int jtl = 0; jtl < 2; ++jtl)
            #pragma unroll
            for (int mt = 0; mt < 4; ++mt) {
                float p0 = exp2f(st[jtl][mt][0]);
                float p1 = exp2f(st[jtl][mt][1]);
                float p2 = exp2f(st[jtl][mt][2]);
                float p3 = exp2f(st[jtl][mt][3]);
                *(uint2*)&Ps[(strip + mt * 16 + ln) * PZ + hf * 32 + jtl * 16 + quad * 4] =
                    pk4(p0, p1, p2, p3);
            }
        // PV + row sums (ones-fragment MFMA; in-wave Ps RAW is in-order)
        bf16x8 ap[4];
        #pragma unroll
        for (int mt = 0; mt < 4; ++mt)
            ap[mt] = *(const bf16x8*)&Ps[(strip + mt * 16 + ln) * PZ + hf * 32 + quad * 8];
        #pragma unroll
        for (int mt = 0; mt < 4; ++mt)
            lsum_acc[mt] = __builtin_amdgcn_mfma_f32_16x16x32_bf16(ap[mt], ones, lsum_acc[mt], 0, 0, 0);
        #pragma unroll
        for (int dt = 0; dt < 8; ++dt) {
            bf16x8 bv = *(const bf16x8*)&Vc[(dt * 16 + ln) * 72 + hf * 32 + quad * 8];
            #pragma unroll
            for (int mt = 0; mt < 4; ++mt)
                o_acc[mt][dt] = __builtin_amdgcn_mfma_f32_16x16x32_bf16(ap[mt], bv, o_acc[mt][dt], 0, 0, 0);
        }
        // stage next tile into idle buffer, then single barrier
        if (pf1) {
            #pragma unroll
            for (int i = 0; i < 2; ++i) {
                int c = t + 512 * i;
                *(uint4*)&Ks[cur ^ 1][(c >> 4) * 136 + (c & 15) * 8] = kxA[i];
                *(uint4*)&Vs[cur ^ 1][(c >> 3) * 72 + (c & 7) * 8] = vxA[i];
            }
        }
        __syncthreads();
        if (pf2) {
            kxA[0] = kxB[0]; kxA[1] = kxB[1];
            vxA[0] = vxB[0]; vxA[1] = vxB[1];
        }
        cur ^= 1;
    }

    // lsum: D layout row=quad*4+r, col=ln (all cols equal) -> float4 store, 4-way split
    const int os = sp * 2 + hf;
    if (ln == 0) {
        #pragma unroll
        for (int mt = 0; mt < 4; ++mt)
            *(f32x4*)&lsumG[(size_t)(os * 4 + h) * LDIM + i0 + strip + mt * 16 + quad * 4] = lsum_acc[mt];
    }

    // merge hf pairs through LDS (f32 scratch over Ps), hf==0 holds the sum
    float* Pf = (float*)Ps;
    const int sgrp = strip >> 6;
    #pragma unroll
    for (int r2 = 0; r2 < 4; ++r2) {
        if (hf == 1) {
            #pragma unroll
            for (int e = 0; e < 2; ++e) {
                int dt = r2 * 2 + e;
                #pragma unroll
                for (int mt = 0; mt < 4; ++mt) {
                    int idx = ((((sgrp * 4 + mt) * 2 + e) * 4 + quad) * 16 + ln) * 4;
                    *(f32x4*)&Pf[idx] = o_acc[mt][dt];
                }
            }
        }
        __syncthreads();
        if (hf == 0) {
            #pragma unroll
            for (int e = 0; e < 2; ++e) {
                int dt = r2 * 2 + e;
                #pragma unroll
                for (int mt = 0; mt < 4; ++mt) {
                    int idx = ((((sgrp * 4 + mt) * 2 + e) * 4 + quad) * 16 + ln) * 4;
                    f32x4 v = *(const f32x4*)&Pf[idx];
                    o_acc[mt][dt] += v;
                }
            }
        }
        __syncthreads();
    }

    if (hf == 0) {
        u16* og = Opart + (size_t)sp * 512 * LDIM;
        #pragma unroll
        for (int mt = 0; mt < 4; ++mt)
            #pragma unroll
            for (int dt = 0; dt < 8; ++dt) {
                f32x4 o = o_acc[mt][dt];
                *(uint2*)(og + (size_t)(h * 128 + dt * 16 + ln) * LDIM + i0 + strip + mt * 16 + quad * 4) =
                    pk4(o[0], o[1], o[2], o[3]);
            }
    }
}

// combine: out[c][l] = clip((xs + (O0+O1)/(sum_os l_os)) / sqrt(2))
__global__ void k_combine(const u16* __restrict__ o01, const float* __restrict__ lsumG,
                          const float* __restrict__ xs_cl, float* __restrict__ out) {
    int idx = blockIdx.x * 256 + threadIdx.x;
    int c = idx >> 11;
    int lq = (idx & 2047) * 4;
    int h = c >> 7;
    uint2 a0 = *(const uint2*)(o01 + (size_t)c * LDIM + lq);
    uint2 a1 = *(const uint2*)(o01 + (size_t)(512 + c) * LDIM + lq);
    float4 s0 = *(const float4*)(lsumG + (size_t)h * LDIM + lq);
    float4 s1 = *(const float4*)(lsumG + (size_t)(4 + h) * LDIM + lq);
    float4 s2 = *(const float4*)(lsumG + (size_t)(8 + h) * LDIM + lq);
    float4 s3 = *(const float4*)(lsumG + (size_t)(12 + h) * LDIM + lq);
    float4 xv = *(const float4*)(xs_cl + (size_t)c * LDIM + lq);
    const u16* p0 = (const u16*)&a0;
    const u16* p1 = (const u16*)&a1;
    float ls[4] = {s0.x + s1.x + s2.x + s3.x, s0.y + s1.y + s2.y + s3.y,
                   s0.z + s1.z + s2.z + s3.z, s0.w + s1.w + s2.w + s3.w};
    float xi[4] = {xv.x, xv.y, xv.z, xv.w};
    float4 o;
    float* op = (float*)&o;
    #pragma unroll
    for (int r = 0; r < 4; ++r) {
        float ov = (bf2f(p0[r]) + bf2f(p1[r])) / ls[r];
        float val = (xi[r] + ov) * kInvSqrt2;
        op[r] = fminf(fmaxf(val, -256.f), 256.f);
    }
    *(float4*)(out + (size_t)c * LDIM + lq) = o;
}

// ---------------------------------------------------------------------------
extern "C" void kernel_launch(void* const* d_in, const int* in_sizes, int n_in,
                              void* d_out, int out_size, void* d_ws, size_t ws_size,
                              hipStream_t stream) {
    const float* x      = (const float*)d_in[0];
    const float* emb    = (const float*)d_in[1];
    const float* pos    = (const float*)d_in[2];
    const float* eg     = (const float*)d_in[3];
    const float* w_res0 = (const float*)d_in[4];
    const float* w_depth= (const float*)d_in[5];
    const float* w_emb  = (const float*)d_in[6];
    const float* w_res1 = (const float*)d_in[7];
    const float* w_qk   = (const float*)d_in[8];
    const float* w_v    = (const float*)d_in[9];
    float* out = (float*)d_out;

    char* W = (char*)d_ws;
    const size_t MiB = 1024 * 1024;
    u16*   xt    = (u16*)(W);                      // 8 MiB
    u16*   pos_t = (u16*)(W + 8 * MiB);            // 8 MiB; later vt2
    u16*   w0b   = (u16*)(W + 16 * MiB);
    u16*   w1b   = (u16*)(W + 17 * MiB);
    u16*   wqb   = (u16*)(W + 18 * MiB);
    u16*   wvb   = (u16*)(W + 20 * MiB);
    u16*   wtb   = (u16*)(W + 20 * MiB + 512 * 1024);
    float* cvec  = (float*)(W + 22 * MiB + 768 * 1024);
    float* rnv   = (float*)(W + 22 * MiB + 896 * 1024);
    float* lsumG = (float*)(W + 23 * MiB);         // 512 KiB (16 x 8192 f32)
    u16*   bufD  = (u16*)(W + 24 * MiB);           // 16 MiB: y1t -> qk_t -> xs_cl
    u16*   bufE  = (u16*)(W + 40 * MiB);           // 16 MiB: y2t -> pe_t -> v_t -> O sp0/1
    u16*   k_t   = (u16*)(W + 56 * MiB);           // 8 MiB
    u16*   xs_t  = (u16*)(W + 64 * MiB);           // 8 MiB
    u16*   bufH  = (u16*)(W + 72 * MiB);           // 8 MiB: y3t -> q_t
    u16*   vt2   = pos_t;
    float* xs_cl = (float*)bufD;

    k_prep_w<<<2048, 256, 0, stream>>>(w_res0, w_res1, w_qk, w_v, w_depth,
                                       w0b, w1b, wqb, wvb, wtb);
    k_emb<<<256, 256, 0, stream>>>(w_emb, emb, eg, cvec);
    k_rn<<<128, 256, 0, stream>>>(x, rnv);
    k_tr2<<<dim3(128, 8), 256, 0, stream>>>(x, rnv, xt);
    k_tr2<<<dim3(128, 8), 256, 0, stream>>>(pos, nullptr, pos_t);
    k_gemm_tm<<<dim3(64, 8), 256, 0, stream>>>(xt, w0b, bufD, 512, 1024, kInvSqrt512);
    k_gconv_tm<<<dim3(128, 8), 256, 0, stream>>>(bufD, wtb, cvec, bufE);
    k_gemm_tm<<<dim3(64, 4), 256, 0, stream>>>(bufE, w1b, bufH, 1024, 512, kInvSqrt1024);
    k_mpsum_t<<<2048, 256, 0, stream>>>(xt, bufH, xs_t);
    k_pe_t<<<2048, 256, 0, stream>>>(xs_t, pos_t, bufE);
    k_gemm_tm<<<dim3(64, 8), 256, 0, stream>>>(bufE, wqb, bufD, 1024, 1024, kInvSqrt1024);
    k_norm_qk2<<<2048, 256, 0, stream>>>(bufD, bufH, k_t);
    k_tr_b2x<<<1024, 256, 0, stream>>>(xs_t, xs_cl, 0);
    k_gemm_tm<<<dim3(64, 4), 256, 0, stream>>>(xs_t, wvb, bufE, 512, 512, kInvSqrt512);
    k_norm_v2<<<2048, 256, 0, stream>>>(bufE);
    k_tr_b2x<<<1024, 256, 0, stream>>>(bufE, vt2, 1);
    // attention partials (K-split 2, dbuf LDS, 1 barrier/iter)
    k_attn7<<<256, 512, 0, stream>>>(bufH, k_t, vt2, bufE, lsumG);
    k_combine<<<4096, 256, 0, stream>>>(bufE, lsumG, xs_cl, out);
}

// Round 9
// 511.111 us; speedup vs baseline: 1.5814x; 1.5814x over previous
//
#include <hip/hip_runtime.h>
#include <math.h>

#define LDIM 8192   // H*W = 16*512
#define NC   512
#define NM   1024

typedef unsigned short u16;
typedef unsigned int   u32;
typedef short bf16x8 __attribute__((ext_vector_type(8)));
typedef float f32x4  __attribute__((ext_vector_type(4)));

static constexpr float kEps        = 1e-4f;
static constexpr float kInvSqrt512 = 0.044194173824159216f;
static constexpr float kInvSqrt1024= 0.03125f;
static constexpr float kInvSqrt1152= 0.029462782549439483f;
static constexpr float kQScale     = 0.08838834764831845f;   // 1/sqrt(128)
static constexpr float kInvSqrt2   = 0.7071067811865476f;
static constexpr float kInvSilu    = 1.0f / 0.596f;

__device__ __forceinline__ u16 f2bf(float f) {
    u32 u = __float_as_uint(f);
    u += 0x7fff + ((u >> 16) & 1);
    return (u16)(u >> 16);
}
__device__ __forceinline__ float bf2f(u16 h) { return __uint_as_float((u32)h << 16); }
__device__ __forceinline__ uint2 pk4(float a, float b, float c, float d) {
    uint2 r;
    r.x = (u32)f2bf(a) | ((u32)f2bf(b) << 16);
    r.y = (u32)f2bf(c) | ((u32)f2bf(d) << 16);
    return r;
}
// async global->LDS, 16 B per lane; HW dest = ldsbase + lane*16 (wave-uniform base)
__device__ __forceinline__ void gll16(const u16* g, u16* l) {
    __builtin_amdgcn_global_load_lds(
        (const __attribute__((address_space(1))) unsigned int*)g,
        (__attribute__((address_space(3))) unsigned int*)l, 16, 0, 0);
}

// ---------------------------------------------------------------------------
#define N_W0 524288
#define N_W1 524288
#define N_WQ 1048576
#define N_WV 262144
#define N_WT 1179648
__global__ void k_prep_w(const float* __restrict__ w0, const float* __restrict__ w1,
                         const float* __restrict__ wq, const float* __restrict__ wv,
                         const float* __restrict__ wd,
                         u16* __restrict__ w0b, u16* __restrict__ w1b,
                         u16* __restrict__ wqb, u16* __restrict__ wvb,
                         u16* __restrict__ wtb) {
    const int total = N_W0 + N_W1 + N_WQ + N_WV + N_WT;
    for (int i = blockIdx.x * 256 + threadIdx.x; i < total; i += gridDim.x * 256) {
        int idx = i;
        if (idx < N_W0) { w0b[idx] = f2bf(w0[idx]); continue; }
        idx -= N_W0;
        if (idx < N_W1) { w1b[idx] = f2bf(w1[idx]); continue; }
        idx -= N_W1;
        if (idx < N_WQ) { wqb[idx] = f2bf(wq[idx]); continue; }
        idx -= N_WQ;
        if (idx < N_WV) { wvb[idx] = f2bf(wv[idx]); continue; }
        idx -= N_WV;
        int tap = idx >> 17;
        int rem = idx & 131071;
        int co = rem >> 7, ci = rem & 127;
        wtb[idx] = f2bf(wd[(co * 128 + ci) * 9 + tap]);
    }
}

__global__ void k_emb(const float* __restrict__ w_emb, const float* __restrict__ emb,
                      const float* __restrict__ eg, float* __restrict__ cvec) {
    int wave = threadIdx.x >> 6, lane = threadIdx.x & 63;
    int m = blockIdx.x * 4 + wave;
    float s = 0.f;
    for (int e = lane; e < 512; e += 64) s += w_emb[(size_t)m * 512 + e] * emb[e];
    for (int off = 32; off; off >>= 1) s += __shfl_down(s, off);
    if (lane == 0) cvec[m] = eg[0] * kInvSqrt512 * s + 1.0f;
}

// ---------------------------------------------------------------------------
__global__ void k_rn(const float* __restrict__ x, float* __restrict__ rn) {
    __shared__ float red[4][64];
    int t = threadIdx.x;
    int ll = t & 63, qtr = t >> 6;
    int l = blockIdx.x * 64 + ll;
    float ss = 0.f;
    for (int c = qtr * 128; c < (qtr + 1) * 128; ++c) {
        float v = x[(size_t)c * LDIM + l];
        ss += v * v;
    }
    red[qtr][ll] = ss;
    __syncthreads();
    if (t < 64)
        rn[blockIdx.x * 64 + t] =
            1.f / (kEps + sqrtf((red[0][t] + red[1][t] + red[2][t] + red[3][t]) * (1.0f / 512.0f)));
}

__launch_bounds__(256)
__global__ void k_tr2(const float* __restrict__ in, const float* __restrict__ rn,
                      u16* __restrict__ out) {
    __shared__ float T[64][65];
    const int t = threadIdx.x;
    const int l0 = blockIdx.x * 64, c0 = blockIdx.y * 64;
    #pragma unroll
    for (int i = 0; i < 16; ++i) {
        int idx = t + 256 * i;
        int ci = idx >> 6, ll = idx & 63;
        T[ci][ll] = in[(size_t)(c0 + ci) * LDIM + l0 + ll];
    }
    __syncthreads();
    int lo = t >> 2, cc0 = (t & 3) * 16;
    float s = rn ? rn[l0 + lo] : 1.0f;
    u16 tmp[16];
    #pragma unroll
    for (int j = 0; j < 16; ++j) tmp[j] = f2bf(T[cc0 + j][lo] * s);
    u16* dst = out + (size_t)(l0 + lo) * 512 + c0 + cc0;
    *(uint4*)dst = *(uint4*)&tmp[0];
    *(uint4*)(dst + 8) = *(uint4*)&tmp[8];
}

__launch_bounds__(256)
__global__ void k_tr_b2x(const u16* __restrict__ in, void* __restrict__ outp, int mode) {
    __shared__ u16 T[64][72];
    const int t = threadIdx.x;
    const int lt = blockIdx.x & 127, ct = blockIdx.x >> 7;
    const int l0 = lt * 64, c0 = ct * 64;
    #pragma unroll
    for (int i = 0; i < 2; ++i) {
        int c = t + 256 * i;
        int ll = c >> 3, cc = c & 7;
        *(uint4*)&T[ll][cc * 8] = *(const uint4*)(in + (size_t)(l0 + ll) * 512 + c0 + cc * 8);
    }
    __syncthreads();
    int ll = t & 63;
    if (mode == 0) {
        float* out = (float*)outp;
        #pragma unroll
        for (int i = 0; i < 16; ++i) {
            int cj = (t >> 6) + 4 * i;
            out[(size_t)(c0 + cj) * LDIM + l0 + ll] = bf2f(T[ll][cj]);
        }
    } else {
        u16* out = (u16*)outp;
        #pragma unroll
        for (int i = 0; i < 16; ++i) {
            int cj = (t >> 6) + 4 * i;
            out[(size_t)(c0 + cj) * LDIM + l0 + ll] = T[ll][cj];
        }
    }
}

// ---------------------------------------------------------------------------
// bf16 NT-GEMM with global_load_lds(16B) staging + XOR-swizzled LDS layout.
// Rows are 64 u16 (128 B, unpadded, GLL-compatible); chunk c of row r lives at
// LDS position c^(r&7) -> ds_read_b128 fragments hit the 2-way floor.
// Single-buffered (m97 structure); overlap comes from multi-block co-residency.
__launch_bounds__(256, 2)
__global__ void k_gemm_tm(const u16* __restrict__ Xt, const u16* __restrict__ W,
                          u16* __restrict__ Out, int K, int M, float scale) {
    __shared__ u16 sm[17408];          // Xs[128*64] + Ws[128*64]; Sout[128*136] union
    u16* Xs = sm;
    u16* Ws = sm + 8192;
    u16* Sout = sm;
    const int t = threadIdx.x;
    const int lane = t & 63, wave = t >> 6;
    const int quad = lane >> 4, ln = lane & 15;
    const int l0 = blockIdx.x * 128, m0 = blockIdx.y * 128;
    const int cs = (wave & 1) * 64, ls = (wave >> 1) * 64;
    const int rsub = lane >> 3;        // row-within-8 for staging
    const int gch  = (lane & 7) ^ rsub; // swizzled source chunk (const per lane)

    f32x4 acc[4][4] = {};
    for (int k0 = 0; k0 < K; k0 += 64) {
        // stage: 4 GLL per wave per operand; 8 rows per instruction
        #pragma unroll
        for (int i = 0; i < 4; ++i) {
            int rbase = wave * 32 + i * 8;
            int row = rbase + rsub;
            gll16(Xt + (size_t)(l0 + row) * K + k0 + gch * 8, &Xs[rbase * 64]);
            gll16(W  + (size_t)(m0 + row) * K + k0 + gch * 8, &Ws[rbase * 64]);
        }
        __syncthreads();   // drains GLL (vmcnt) for all waves
        #pragma unroll
        for (int ks = 0; ks < 2; ++ks) {
            bf16x8 af[4], bf[4];
            #pragma unroll
            for (int mt = 0; mt < 4; ++mt)
                af[mt] = *(const bf16x8*)&Ws[(cs + mt * 16 + ln) * 64 + (((ks * 4 + quad) ^ (ln & 7)) * 8)];
            #pragma unroll
            for (int nt = 0; nt < 4; ++nt)
                bf[nt] = *(const bf16x8*)&Xs[(ls + nt * 16 + ln) * 64 + (((ks * 4 + quad) ^ (ln & 7)) * 8)];
            #pragma unroll
            for (int mt = 0; mt < 4; ++mt)
                #pragma unroll
                for (int nt = 0; nt < 4; ++nt)
                    acc[mt][nt] = __builtin_amdgcn_mfma_f32_16x16x32_bf16(af[mt], bf[nt], acc[mt][nt], 0, 0, 0);
        }
        __syncthreads();   // all reads done before next stage overwrites
    }
    // epilogue via LDS gather: Sout[l][co]
    #pragma unroll
    for (int mt = 0; mt < 4; ++mt)
        #pragma unroll
        for (int nt = 0; nt < 4; ++nt) {
            f32x4 a = acc[mt][nt];
            *(uint2*)&Sout[(ls + nt * 16 + ln) * 136 + cs + mt * 16 + quad * 4] =
                pk4(a[0] * scale, a[1] * scale, a[2] * scale, a[3] * scale);
        }
    __syncthreads();
    #pragma unroll
    for (int i = 0; i < 8; ++i) {
        int c = t + 256 * i;
        int row = c >> 4, cc = c & 15;
        *(uint4*)(Out + (size_t)(l0 + row) * M + m0 + cc * 8) = *(uint4*)&Sout[row * 136 + cc * 8];
    }
}

// ---------------------------------------------------------------------------
__launch_bounds__(256, 4)
__global__ void k_gconv_tm(const u16* __restrict__ y1t, const u16* __restrict__ wtb,
                           const float* __restrict__ cvec, u16* __restrict__ y2t) {
    __shared__ u16 sm[9792];
    u16* Y = sm;
    u16* Sout = sm;
    const int t = threadIdx.x;
    const int lane = t & 63, wave = t >> 6;
    const int quad = lane >> 4, ln = lane & 15;
    const int l0 = blockIdx.x * 64;
    const int m0 = blockIdx.y * 128;
    const int g = m0 >> 7;

    for (int c = t; c < 1152; c += 256) {
        int row = c >> 4, cc = c & 15;
        int gl = l0 - 4 + row;
        gl = min(max(gl, 0), LDIM - 1);
        *(uint4*)&Y[row * 136 + cc * 8] = *(const uint4*)(y1t + (size_t)gl * 1024 + g * 128 + cc * 8);
    }
    __syncthreads();

    f32x4 acc[2][4] = {};
    const bf16x8 zv = {};
    for (int tap = 0; tap < 9; ++tap) {
        #pragma unroll
        for (int ks = 0; ks < 4; ++ks) {
            bf16x8 af[2], bfr[4];
            #pragma unroll
            for (int mt = 0; mt < 2; ++mt)
                af[mt] = *(const bf16x8*)(wtb + ((size_t)tap * 1024 + m0 + wave * 32 + mt * 16 + ln) * 128 + ks * 32 + quad * 8);
            #pragma unroll
            for (int nt = 0; nt < 4; ++nt) {
                bfr[nt] = *(const bf16x8*)&Y[(nt * 16 + ln + tap) * 136 + ks * 32 + quad * 8];
                int w = ((l0 + nt * 16 + ln) & 511) + tap - 4;
                bool ok = (w >= 0) && (w < 512);
                bfr[nt] = ok ? bfr[nt] : zv;
            }
            #pragma unroll
            for (int mt = 0; mt < 2; ++mt)
                #pragma unroll
                for (int nt = 0; nt < 4; ++nt)
                    acc[mt][nt] = __builtin_amdgcn_mfma_f32_16x16x32_bf16(af[mt], bfr[nt], acc[mt][nt], 0, 0, 0);
        }
    }
    __syncthreads();
    #pragma unroll
    for (int mt = 0; mt < 2; ++mt) {
        float4 cv = *(const float4*)(cvec + m0 + wave * 32 + mt * 16 + quad * 4);
        #pragma unroll
        for (int nt = 0; nt < 4; ++nt) {
            float z[4], o[4];
            #pragma unroll
            for (int r = 0; r < 4; ++r) {
                z[r] = acc[mt][nt][r] * kInvSqrt1152 * ((const float*)&cv)[r];
                float sig = 1.0f / (1.0f + __expf(-z[r]));
                o[r] = z[r] * sig * kInvSilu;
            }
            *(uint2*)&Sout[(nt * 16 + ln) * 136 + wave * 32 + mt * 16 + quad * 4] =
                pk4(o[0], o[1], o[2], o[3]);
        }
    }
    __syncthreads();
    #pragma unroll
    for (int i = 0; i < 4; ++i) {
        int c = t + 256 * i;
        int row = c >> 4, cc = c & 15;
        *(uint4*)(y2t + (size_t)(l0 + row) * 1024 + m0 + cc * 8) = *(uint4*)&Sout[row * 136 + cc * 8];
    }
}

// ---------------------------------------------------------------------------
// fused: xs = (xt + y3)/sqrt(2);  pe[l][2c]=xs, pe[l][2c+1]=xs*pos
__global__ void k_mpspe(const u16* __restrict__ xt, const u16* __restrict__ y3,
                        const u16* __restrict__ pos, u16* __restrict__ xs_t,
                        u16* __restrict__ pe) {
    int idx = blockIdx.x * 256 + threadIdx.x;
    int l = idx >> 6, cq = idx & 63;
    size_t src = (size_t)l * 512 + cq * 8;
    uint4 av = *(const uint4*)(xt + src);
    uint4 bv = *(const uint4*)(y3 + src);
    uint4 pv = *(const uint4*)(pos + src);
    const u16* ap = (const u16*)&av;
    const u16* bp = (const u16*)&bv;
    const u16* pp = (const u16*)&pv;
    u16 xs8[8], o[16];
    #pragma unroll
    for (int i = 0; i < 8; ++i) {
        float xs = (bf2f(ap[i]) + bf2f(bp[i])) * kInvSqrt2;
        xs8[i] = f2bf(xs);
        o[2 * i] = xs8[i];
        o[2 * i + 1] = f2bf(bf2f(xs8[i]) * bf2f(pp[i]));
    }
    *(uint4*)(xs_t + src) = *(uint4*)xs8;
    u16* dst = pe + (size_t)l * 1024 + cq * 16;
    *(uint4*)dst = *(uint4*)&o[0];
    *(uint4*)(dst + 8) = *(uint4*)&o[8];
}

// ---------------------------------------------------------------------------
__global__ void k_norm_qk2(const u16* __restrict__ qk, u16* __restrict__ q_t,
                           u16* __restrict__ k_t) {
    int wave = threadIdx.x >> 6, lane = threadIdx.x & 63;
    int l = blockIdx.x * 4 + wave;
    const u16* row = qk + (size_t)l * 1024 + lane * 16;
    uint4 a = *(const uint4*)row;
    uint4 b = *(const uint4*)(row + 8);
    const u16* vp = (const u16*)&a;
    const u16* wp = (const u16*)&b;
    float v[16];
    #pragma unroll
    for (int i = 0; i < 8; ++i) { v[i] = bf2f(vp[i]); v[8 + i] = bf2f(wp[i]); }
    float ss0 = 0.f, ss1 = 0.f;
    #pragma unroll
    for (int i = 0; i < 8; ++i) { ss0 += v[2 * i] * v[2 * i]; ss1 += v[2 * i + 1] * v[2 * i + 1]; }
    #pragma unroll
    for (int off = 1; off < 16; off <<= 1) {
        ss0 += __shfl_xor(ss0, off);
        ss1 += __shfl_xor(ss1, off);
    }
    float rn0 = kQScale / (kEps + sqrtf(ss0 * (1.0f / 128.0f)));
    float rn1 = 1.0f / (kEps + sqrtf(ss1 * (1.0f / 128.0f)));
    int h = lane >> 4;
    u16 qo[8], ko[8];
    #pragma unroll
    for (int i = 0; i < 8; ++i) {
        qo[i] = f2bf(v[2 * i] * rn0);
        ko[i] = f2bf(v[2 * i + 1] * rn1);
    }
    size_t dst = ((size_t)h * LDIM + l) * 128 + (lane & 15) * 8;
    *(uint4*)(q_t + dst) = *(uint4*)qo;
    *(uint4*)(k_t + dst) = *(uint4*)ko;
}

__global__ void k_norm_v2(u16* __restrict__ v_t) {
    int wave = threadIdx.x >> 6, lane = threadIdx.x & 63;
    int l = blockIdx.x * 4 + wave;
    u16* p = v_t + (size_t)l * 512 + lane * 8;
    uint4 a = *(const uint4*)p;
    const u16* vp = (const u16*)&a;
    float v[8], ss = 0.f;
    #pragma unroll
    for (int i = 0; i < 8; ++i) { v[i] = bf2f(vp[i]); ss += v[i] * v[i]; }
    #pragma unroll
    for (int off = 1; off < 16; off <<= 1) ss += __shfl_xor(ss, off);
    float rn = 1.0f / (kEps + sqrtf(ss * (1.0f / 128.0f)));
    u16 o[8];
    #pragma unroll
    for (int i = 0; i < 8; ++i) o[i] = f2bf(v[i] * rn);
    *(uint4*)p = *(uint4*)o;
}

// ---------------------------------------------------------------------------
// MFMA flash attention v5 (reverted verbatim — best measured: 266 us).
// 256 blocks x 512 threads; K-split 2; combo = b&7 -> one K/V slice per XCD;
// 8 waves/block (2 waves/SIMD); wave owns a 32-row Q strip; fixed-max softmax.
#define PSP 40
__launch_bounds__(512, 1)
__global__ void k_attn5(const u16* __restrict__ q_t, const u16* __restrict__ k_t,
                        const u16* __restrict__ vt2, u16* __restrict__ Opart,
                        float* __restrict__ lsumG) {
    __shared__ u16 Ks[64 * 136];    // [j][d]
    __shared__ u16 Vs[128 * 72];    // [d][j]
    __shared__ u16 Ps[256 * PSP];   // [i][j-half], 8 wave-strips of 32 rows
    const int t = threadIdx.x;
    const int lane = t & 63, wave = t >> 6;   // 0..7
    const int quad = lane >> 4, ln = lane & 15;
    const int b = blockIdx.x;
    const int h = (b >> 1) & 3, sp = b & 1;
    const int i0 = (b >> 3) * 256;
    const int jb0 = sp * 4096, jend = jb0 + 4096;
    const u16* qg = q_t + (size_t)h * LDIM * 128;
    const u16* kg = k_t + (size_t)h * LDIM * 128;
    const u16* vg = vt2 + (size_t)h * 128 * LDIM;

    bf16x8 qf[2][4];
    #pragma unroll
    for (int mt = 0; mt < 2; ++mt) {
        int row = i0 + wave * 32 + mt * 16 + ln;
        #pragma unroll
        for (int ks = 0; ks < 4; ++ks)
            qf[mt][ks] = *(const bf16x8*)(qg + (size_t)row * 128 + ks * 32 + quad * 8);
    }

    f32x4 o_acc[2][8] = {};
    float lsum[2] = {};

    #pragma unroll
    for (int i = 0; i < 2; ++i) {
        int c = t + 512 * i;
        *(uint4*)&Ks[(c >> 4) * 136 + (c & 15) * 8] =
            *(const uint4*)(kg + (size_t)(jb0 + (c >> 4)) * 128 + (c & 15) * 8);
        *(uint4*)&Vs[(c >> 3) * 72 + (c & 7) * 8] =
            *(const uint4*)(vg + (size_t)(c >> 3) * LDIM + jb0 + (c & 7) * 8);
    }
    __syncthreads();

    const int istrip = wave * 32;

    for (int jb = jb0; jb < jend; jb += 64) {
        uint4 kx[2], vx[2];
        const bool pf = (jb + 64 < jend);
        if (pf) {
            #pragma unroll
            for (int i = 0; i < 2; ++i) {
                int c = t + 512 * i;
                kx[i] = *(const uint4*)(kg + (size_t)(jb + 64 + (c >> 4)) * 128 + (c & 15) * 8);
                vx[i] = *(const uint4*)(vg + (size_t)(c >> 3) * LDIM + jb + 64 + (c & 7) * 8);
            }
        }
        #pragma unroll
        for (int half = 0; half < 2; ++half) {
            #pragma unroll
            for (int jt = half * 2; jt < half * 2 + 2; ++jt) {
                f32x4 st[2] = {};
                #pragma unroll
                for (int ks = 0; ks < 4; ++ks) {
                    bf16x8 af = *(const bf16x8*)&Ks[(jt * 16 + ln) * 136 + ks * 32 + quad * 8];
                    #pragma unroll
                    for (int mt = 0; mt < 2; ++mt)
                        st[mt] = __builtin_amdgcn_mfma_f32_16x16x32_bf16(af, qf[mt][ks], st[mt], 0, 0, 0);
                }
                #pragma unroll
                for (int mt = 0; mt < 2; ++mt) {
                    float p0 = __expf(st[mt][0]);
                    float p1 = __expf(st[mt][1]);
                    float p2 = __expf(st[mt][2]);
                    float p3 = __expf(st[mt][3]);
                    lsum[mt] += p0 + p1 + p2 + p3;
                    *(uint2*)&Ps[(istrip + mt * 16 + ln) * PSP + (jt - half * 2) * 16 + quad * 4] =
                        pk4(p0, p1, p2, p3);
                }
            }
            bf16x8 ap[2];
            #pragma unroll
            for (int mt = 0; mt < 2; ++mt)
                ap[mt] = *(const bf16x8*)&Ps[(istrip + mt * 16 + ln) * PSP + quad * 8];
            #pragma unroll
            for (int dt = 0; dt < 8; ++dt) {
                bf16x8 bv = *(const bf16x8*)&Vs[(dt * 16 + ln) * 72 + half * 32 + quad * 8];
                #pragma unroll
                for (int mt = 0; mt < 2; ++mt)
                    o_acc[mt][dt] = __builtin_amdgcn_mfma_f32_16x16x32_bf16(ap[mt], bv, o_acc[mt][dt], 0, 0, 0);
            }
        }
        __syncthreads();
        if (pf) {
            #pragma unroll
            for (int i = 0; i < 2; ++i) {
                int c = t + 512 * i;
                *(uint4*)&Ks[(c >> 4) * 136 + (c & 15) * 8] = kx[i];
                *(uint4*)&Vs[(c >> 3) * 72 + (c & 7) * 8] = vx[i];
            }
        }
        __syncthreads();
    }

    #pragma unroll
    for (int mt = 0; mt < 2; ++mt) {
        float s = lsum[mt];
        s += __shfl_xor(s, 16);
        s += __shfl_xor(s, 32);
        if (quad == 0)
            lsumG[(size_t)(sp * 4 + h) * LDIM + i0 + istrip + mt * 16 + ln] = s;
    }
    u16* og = Opart + (size_t)sp * 512 * LDIM;
    #pragma unroll
    for (int mt = 0; mt < 2; ++mt)
        #pragma unroll
        for (int dt = 0; dt < 8; ++dt) {
            f32x4 o = o_acc[mt][dt];
            *(uint2*)(og + (size_t)(h * 128 + dt * 16 + ln) * LDIM + i0 + istrip + mt * 16 + quad * 4) =
                pk4(o[0], o[1], o[2], o[3]);
        }
}

// combine: out[c][l] = clip((xs + (O0+O1)/(l0+l1)) / sqrt(2))
__global__ void k_combine(const u16* __restrict__ Opart, const float* __restrict__ lsumG,
                          const float* __restrict__ xs_cl, float* __restrict__ out) {
    int idx = blockIdx.x * 256 + threadIdx.x;
    int c = idx >> 11;
    int lq = (idx & 2047) * 4;
    int h = c >> 7;
    uint2 a = *(const uint2*)(Opart + (size_t)c * LDIM + lq);
    uint2 b = *(const uint2*)(Opart + (size_t)(512 + c) * LDIM + lq);
    float4 s0 = *(const float4*)(lsumG + (size_t)h * LDIM + lq);
    float4 s1 = *(const float4*)(lsumG + (size_t)(4 + h) * LDIM + lq);
    float4 xv = *(const float4*)(xs_cl + (size_t)c * LDIM + lq);
    const u16* ap = (const u16*)&a;
    const u16* bp = (const u16*)&b;
    float ls[4] = {s0.x + s1.x, s0.y + s1.y, s0.z + s1.z, s0.w + s1.w};
    float xi[4] = {xv.x, xv.y, xv.z, xv.w};
    float4 o;
    float* op = (float*)&o;
    #pragma unroll
    for (int r = 0; r < 4; ++r) {
        float ov = (bf2f(ap[r]) + bf2f(bp[r])) / ls[r];
        float val = (xi[r] + ov) * kInvSqrt2;
        op[r] = fminf(fmaxf(val, -256.f), 256.f);
    }
    *(float4*)(out + (size_t)c * LDIM + lq) = o;
}

// ---------------------------------------------------------------------------
extern "C" void kernel_launch(void* const* d_in, const int* in_sizes, int n_in,
                              void* d_out, int out_size, void* d_ws, size_t ws_size,
                              hipStream_t stream) {
    const float* x      = (const float*)d_in[0];
    const float* emb    = (const float*)d_in[1];
    const float* pos    = (const float*)d_in[2];
    const float* eg     = (const float*)d_in[3];
    const float* w_res0 = (const float*)d_in[4];
    const float* w_depth= (const float*)d_in[5];
    const float* w_emb  = (const float*)d_in[6];
    const float* w_res1 = (const float*)d_in[7];
    const float* w_qk   = (const float*)d_in[8];
    const float* w_v    = (const float*)d_in[9];
    float* out = (float*)d_out;

    char* W = (char*)d_ws;
    const size_t MiB = 1024 * 1024;
    u16*   xt    = (u16*)(W);                      // 8 MiB
    u16*   pos_t = (u16*)(W + 8 * MiB);            // 8 MiB; later vt2
    u16*   w0b   = (u16*)(W + 16 * MiB);
    u16*   w1b   = (u16*)(W + 17 * MiB);
    u16*   wqb   = (u16*)(W + 18 * MiB);
    u16*   wvb   = (u16*)(W + 20 * MiB);
    u16*   wtb   = (u16*)(W + 20 * MiB + 512 * 1024);
    float* cvec  = (float*)(W + 22 * MiB + 768 * 1024);
    float* rnv   = (float*)(W + 22 * MiB + 896 * 1024);
    float* lsumG = (float*)(W + 23 * MiB);         // 256 KiB (8 x 8192 f32)
    u16*   bufD  = (u16*)(W + 24 * MiB);           // 16 MiB: y1t -> qk_t -> xs_cl
    u16*   bufE  = (u16*)(W + 40 * MiB);           // 16 MiB: y2t -> pe_t -> v_t -> Opart
    u16*   k_t   = (u16*)(W + 56 * MiB);           // 8 MiB
    u16*   xs_t  = (u16*)(W + 64 * MiB);           // 8 MiB
    u16*   bufH  = (u16*)(W + 72 * MiB);           // 8 MiB: y3t -> q_t
    u16*   vt2   = pos_t;
    float* xs_cl = (float*)bufD;

    k_prep_w<<<2048, 256, 0, stream>>>(w_res0, w_res1, w_qk, w_v, w_depth,
                                       w0b, w1b, wqb, wvb, wtb);
    k_emb<<<256, 256, 0, stream>>>(w_emb, emb, eg, cvec);
    k_rn<<<128, 256, 0, stream>>>(x, rnv);
    k_tr2<<<dim3(128, 8), 256, 0, stream>>>(x, rnv, xt);
    k_tr2<<<dim3(128, 8), 256, 0, stream>>>(pos, nullptr, pos_t);
    k_gemm_tm<<<dim3(64, 8), 256, 0, stream>>>(xt, w0b, bufD, 512, 1024, kInvSqrt512);
    k_gconv_tm<<<dim3(128, 8), 256, 0, stream>>>(bufD, wtb, cvec, bufE);
    k_gemm_tm<<<dim3(64, 4), 256, 0, stream>>>(bufE, w1b, bufH, 1024, 512, kInvSqrt1024);
    // fused xs + pe
    k_mpspe<<<2048, 256, 0, stream>>>(xt, bufH, pos_t, xs_t, bufE);
    k_gemm_tm<<<dim3(64, 8), 256, 0, stream>>>(bufE, wqb, bufD, 1024, 1024, kInvSqrt1024);
    k_norm_qk2<<<2048, 256, 0, stream>>>(bufD, bufH, k_t);
    k_tr_b2x<<<1024, 256, 0, stream>>>(xs_t, xs_cl, 0);
    k_gemm_tm<<<dim3(64, 4), 256, 0, stream>>>(xs_t, wvb, bufE, 512, 512, kInvSqrt512);
    k_norm_v2<<<2048, 256, 0, stream>>>(bufE);
    k_tr_b2x<<<1024, 256, 0, stream>>>(bufE, vt2, 1);
    // attention partials (v5: K-split 2, 8 waves/block, 1 block/CU, XCD-clustered)
    k_attn5<<<256, 512, 0, stream>>>(bufH, k_t, vt2, bufE, lsumG);
    k_combine<<<4096, 256, 0, stream>>>(bufE, lsumG, xs_cl, out);
}